// Round 1
// 2127.250 us; speedup vs baseline: 1.0212x; 1.0212x over previous
//
#include <hip/hip_runtime.h>

typedef unsigned int uint;
typedef unsigned short ushort;
using half8v  = __attribute__((ext_vector_type(8))) _Float16;
using half4v  = __attribute__((ext_vector_type(4))) _Float16;
using float4v = __attribute__((ext_vector_type(4))) float;

#define EPS_SINK 0.0025f
#define INV_EPS_SINK 400.0f
#define EPS_LOG512 0.015595811562598769f

// ---- workspace layout (BYTE offsets), peak ~165 MB ----
static const size_t O_W1   = 0ull;             // 512*512*8 f16 = 4,194,304 B
static const size_t O_W2   = 4194304ull;       // 2,097,152 B each
static const size_t O_W3   = 6291456ull;
static const size_t O_W4   = 8388608ull;
static const size_t O_H0   = 20971520ull;      // 16*512*6400 f16 = 104,857,600 B
static const size_t O_H1   = 125829120ull;     // 16*256*1598 uint = 26,181,632 B
static const size_t O_H2   = 20971520ull;      // alias h0 (dead after conv1)
static const size_t O_H3   = 34045952ull;
static const size_t O_FEATX= 152010752ull;     // 16*512*198 fp32
static const size_t O_FEATY= 158498816ull;
static const size_t O_STATS= 164986880ull;     // 512 floats
// cost phase (weights/h0/h1 all dead).  C stored f16, value = 100*C:
static const size_t O_CXY  = 0ull;             // 8,388,608 B each
static const size_t O_CTXY = 8388608ull;
static const size_t O_CXX  = 16777216ull;
static const size_t O_CYY  = 25165824ull;
static const size_t O_AAX  = 33554432ull;
static const size_t O_AAY  = 33587200ull;
static const size_t O_F    = 33619968ull;      // 3*16*512 fp32
static const size_t O_G    = 33718272ull;

#define GLOAD_LDS16(gp, lp) __builtin_amdgcn_global_load_lds( \
    (const __attribute__((address_space(1))) void*)(gp),       \
    (__attribute__((address_space(3))) void*)(lp), 16, 0, 0)

// ---------------------------------------------------------------------------
// prep_w: convert conv weights fp32 -> single f16. W1 [oc][ic][8 taps];
// W2-4 pair-interleaved [oc][icpair][dt0 icA, dt0 icB, dt1 icA, ...].
// ---------------------------------------------------------------------------
__global__ __launch_bounds__(256) void prep_w(
    const float* __restrict__ W1, const float* __restrict__ W2,
    const float* __restrict__ W3, const float* __restrict__ W4,
    _Float16* __restrict__ w1, _Float16* __restrict__ w2,
    _Float16* __restrict__ w3, _Float16* __restrict__ w4)
{
    const int layer = blockIdx.y;
    const int e = blockIdx.x * 256 + threadIdx.x;
    float v[8];
    _Float16* dh;
    if (layer == 0) {
        const float4 a = *(const float4*)(W1 + (size_t)e * 8);
        const float4 c = *(const float4*)(W1 + (size_t)e * 8 + 4);
        v[0]=a.x; v[1]=a.y; v[2]=a.z; v[3]=a.w; v[4]=c.x; v[5]=c.y; v[6]=c.z; v[7]=c.w;
        dh = w1;
    } else {
        if (e >= 131072) return;
        const float* W = (layer == 1) ? W2 : (layer == 2) ? W3 : W4;
        dh = (layer == 1) ? w2 : (layer == 2) ? w3 : w4;
        const int oc = e >> 8, icp = e & 255;
        const float4 a = *(const float4*)(W + ((size_t)oc * 512 + icp * 2) * 4);
        const float4 c = *(const float4*)(W + ((size_t)oc * 512 + icp * 2 + 1) * 4);
        v[0]=a.x; v[1]=c.x; v[2]=a.y; v[3]=c.y; v[4]=a.z; v[5]=c.z; v[6]=a.w; v[7]=c.w;
    }
    half8v hi;
#pragma unroll
    for (int k = 0; k < 8; ++k) hi[k] = (_Float16)v[k];
    *(half8v*)(dh + (size_t)e * 8) = hi;
}

// ---------------------------------------------------------------------------
// conv0_store: raw conv0 (k=10,s=5) -> h0 f16 [b][512][6400] + GN stats.
// ---------------------------------------------------------------------------
__global__ __launch_bounds__(256) void conv0_store(
    const float* __restrict__ wav, const float* __restrict__ W0,
    _Float16* __restrict__ h0, float* __restrict__ stats)
{
    __shared__ float LW[5120];
    __shared__ float red[2][256];
    const int tid = threadIdx.x;
    for (int e = tid; e < 5120; e += 256) LW[e] = W0[e];

    const int b = blockIdx.y;
    const int t = blockIdx.x * 256 + tid;
    const bool valid = (t < 6399);
    float xv[10];
#pragma unroll
    for (int d = 0; d < 10; ++d) xv[d] = 0.f;
    if (valid) {
        const float* wp = wav + (size_t)b * 32000 + (size_t)t * 5;
#pragma unroll
        for (int d = 0; d < 10; ++d) xv[d] = wp[d];
    }
    __syncthreads();

    float lsum = 0.f, lsq = 0.f;
    _Float16* hb = h0 + (size_t)b * 512 * 6400;
    for (int oc = 0; oc < 512; ++oc) {
        float a = 0.f;
#pragma unroll
        for (int d = 0; d < 10; ++d) a += LW[oc * 10 + d] * xv[d];
        if (valid) {
            hb[(size_t)oc * 6400 + t] = (_Float16)a;
            lsum += a; lsq += a * a;
        }
    }
    red[0][tid] = lsum; red[1][tid] = lsq;
    __syncthreads();
    for (int s2 = 128; s2 > 0; s2 >>= 1) {
        if (tid < s2) { red[0][tid] += red[0][tid + s2]; red[1][tid] += red[1][tid + s2]; }
        __syncthreads();
    }
    if (tid == 0) {
        atomicAdd(&stats[2 * b], red[0][0]);
        atomicAdd(&stats[2 * b + 1], red[1][0]);
    }
}

// ---------------------------------------------------------------------------
// norm_h0: in-place GN0 + affine + ReLU on h0 f16; zeroes tail slot 6399.
// ---------------------------------------------------------------------------
__global__ __launch_bounds__(256) void norm_h0(
    _Float16* __restrict__ h0, const float* __restrict__ stats,
    const float* __restrict__ gamma, const float* __restrict__ beta)
{
    const int row = blockIdx.y;
    const int b = row >> 9, oc = row & 511;
    const int t8 = (blockIdx.x * 256 + threadIdx.x) * 8;
    if (t8 >= 6400) return;
    const float invN = 1.f / (512.f * 6399.f);
    const float mu = stats[2 * b] * invN;
    const float var = stats[2 * b + 1] * invN - mu * mu;
    const float rs = rsqrtf(var + 1e-5f);
    const float sc = rs * gamma[oc];
    const float sh = beta[oc] - mu * sc;
    _Float16* p = h0 + (size_t)row * 6400 + t8;
    half8v v = *(half8v*)p;
#pragma unroll
    for (int k = 0; k < 8; ++k) {
        const float f = (t8 + k < 6399) ? fmaxf((float)v[k] * sc + sh, 0.f) : 0.f;
        v[k] = (_Float16)f;
    }
    *(half8v*)p = v;
}

// ---------------------------------------------------------------------------
// conv1_mfma v2: layer1 (K=8,S=4) from NORMALIZED h0. 128oc x 128t tile,
// 4 waves, 4x4 MFMA tiles/wave. Double-buffered 2-phase K-loop:
//   W staged via global_load_lds (dwordx4, conflict-free [k32l][q][oc][8]),
//   X staged via T14 split (load-early regs -> ds_write after MFMA),
//   one vmcnt(0)+barrier per K-step. XCD-chunked swizzle, oc-tile fastest.
// LDS 51.7 KB -> 3 blocks/CU (grid gives 3.25/CU anyway).
// ---------------------------------------------------------------------------
__global__ __launch_bounds__(256, 3) void conv1_mfma(
    const _Float16* __restrict__ h0,
    const _Float16* __restrict__ w1,
    _Float16* __restrict__ oh, float* __restrict__ stats1)
{
    __shared__ _Float16 LW[2][2][4][128][8];   // 32 KB  [buf][k32l][q][oc][8]
    __shared__ _Float16 LX[2][8][528];         // 16.9 KB [buf][ic][t4]
    __shared__ float red[2][256];

    const int tid  = threadIdx.x;
    const int lane = tid & 63, wv = tid >> 6;
    const int m    = lane & 15, quad = lane >> 4;
    const int wv2  = wv >> 1, wvt = wv & 1;

    // chunked XCD swizzle: 832 blocks = 8 chunks of 104; within chunk y fastest
    const int raw = blockIdx.x;
    const int cid = (raw & 7) * 104 + (raw >> 3);
    const int b   = cid / 52;
    const int r2  = cid - b * 52;
    const int xt  = r2 >> 2, yt = r2 & 3;
    const int ocb = yt * 128;
    const int t0  = xt * 128;
    const int Lout = 1598;

    float4v acc[4][4];
#pragma unroll
    for (int i = 0; i < 4; ++i)
#pragma unroll
        for (int j = 0; j < 4; ++j) acc[i][j] = (float4v){0.f, 0.f, 0.f, 0.f};

    const _Float16* hb = h0 + (size_t)b * 512 * 6400;
    const int gbase = t0 * 4;
    const int lim = 6400 - gbase;              // valid f16s from gbase
    const bool fullx = (gbase + 520 <= 6400);  // only last t-tile is partial

    // --- X stage state: 520 16B-units/iter; thread handles eA, eB (+eC if tid<8)
    const int icA = tid / 65,          uA = tid - icA * 65;
    const int eB  = tid + 256;
    const int icB = eB / 65,           uB = eB - icB * 65;
    const int uC  = (tid + 512) - 455; // ic 7, valid only tid<8
    const _Float16* srcA = hb + (size_t)icA * 6400 + gbase + uA * 8;
    const _Float16* srcB = hb + (size_t)icB * 6400 + gbase + uB * 8;
    const _Float16* srcC = hb + (size_t)7   * 6400 + gbase + uC * 8;
    half8v xr[3];

    // --- W stage state: 16 wave-loads/iter, 4 per wave (e = wv*4+r)
    const _Float16* wsrc[4];
#pragma unroll
    for (int r = 0; r < 4; ++r) {
        const int e = wv * 4 + r;
        const int oh2 = e & 1, q = (e >> 1) & 3, k32l = e >> 3;
        wsrc[r] = w1 + ((size_t)(ocb + oh2 * 64 + lane) * 512 + (k32l * 4 + q)) * 8;
    }

    auto stageW = [&](int buf) {
#pragma unroll
        for (int r = 0; r < 4; ++r) {
            const int e = wv * 4 + r;
            const int oh2 = e & 1, q = (e >> 1) & 3, k32l = e >> 3;
            GLOAD_LDS16(wsrc[r], &LW[buf][k32l][q][oh2 * 64][0]);
            wsrc[r] += 64;                     // 8 ic * 8 taps
        }
    };
    auto loadX = [&]() {
        if (fullx) {
            xr[0] = *(const half8v*)srcA;
            xr[1] = *(const half8v*)srcB;
            if (tid < 8) xr[2] = *(const half8v*)srcC;
        } else {
#pragma unroll
            for (int k = 0; k < 8; ++k) xr[0][k] = (uA * 8 + k < lim) ? srcA[k] : (_Float16)0.f;
#pragma unroll
            for (int k = 0; k < 8; ++k) xr[1][k] = (uB * 8 + k < lim) ? srcB[k] : (_Float16)0.f;
            if (tid < 8) {
#pragma unroll
                for (int k = 0; k < 8; ++k) xr[2][k] = (uC * 8 + k < lim) ? srcC[k] : (_Float16)0.f;
            }
        }
        srcA += 8 * 6400; srcB += 8 * 6400; srcC += 8 * 6400;
    };
    auto storeX = [&](int buf) {
        *(half8v*)&LX[buf][icA][uA * 8] = xr[0];
        *(half8v*)&LX[buf][icB][uB * 8] = xr[1];
        if (tid < 8) *(half8v*)&LX[buf][7][uC * 8] = xr[2];
    };
    auto compute = [&](int buf) {
#pragma unroll
        for (int k32l = 0; k32l < 2; ++k32l) {
            half8v a4[4], bfv[4];
#pragma unroll
            for (int i = 0; i < 4; ++i)
                a4[i] = *(const half8v*)&LW[buf][k32l][quad][wv2 * 64 + i * 16 + m][0];
            const int icl = k32l * 4 + quad;
#pragma unroll
            for (int j = 0; j < 4; ++j) {
                const int tl = wvt * 64 + j * 16 + m;
                const half4v x0 = *(const half4v*)&LX[buf][icl][tl * 4];
                const half4v x1 = *(const half4v*)&LX[buf][icl][tl * 4 + 4];
                bfv[j] = __builtin_shufflevector(x0, x1, 0, 1, 2, 3, 4, 5, 6, 7);
            }
#pragma unroll
            for (int i = 0; i < 4; ++i)
#pragma unroll
                for (int j = 0; j < 4; ++j)
                    acc[i][j] = __builtin_amdgcn_mfma_f32_16x16x32_f16(a4[i], bfv[j], acc[i][j], 0, 0, 0);
        }
    };

    // prologue: stage iter 0 into buf0
    loadX(); stageW(0); storeX(0);
    __syncthreads();

    for (int it = 0; it < 64; it += 2) {
        // phase A: compute buf0, stage it+1 -> buf1 (it <= 62 so it+1 < 64 always)
        loadX(); stageW(1);
        compute(0);
        storeX(1);
        __syncthreads();
        // phase B: compute buf1, stage it+2 -> buf0
        const bool s2 = (it + 2 < 64);
        if (s2) { loadX(); stageW(0); }
        compute(1);
        if (s2) storeX(0);
        __syncthreads();
    }

    // --- epilogue: pack f16 pairs + stats
    float lsum = 0.f, lsq = 0.f;
    uint* ohU = (uint*)oh;
#pragma unroll
    for (int i = 0; i < 4; ++i) {
        const int ocb2 = ocb + wv2 * 64 + i * 16 + quad * 4;
#pragma unroll
        for (int j = 0; j < 4; ++j) {
            const int t = t0 + wvt * 64 + j * 16 + m;
            if (t < Lout) {
#pragma unroll
                for (int pr = 0; pr < 2; ++pr) {
                    const float v0 = acc[i][j][pr * 2], v1 = acc[i][j][pr * 2 + 1];
                    union { uint u; _Float16 h[2]; } pk;
                    pk.h[0] = (_Float16)v0; pk.h[1] = (_Float16)v1;
                    const uint p = (uint)((ocb2 >> 1) + pr);
                    ohU[((size_t)(b * 256 + p)) * Lout + t] = pk.u;
                    lsum += v0 + v1; lsq += v0 * v0 + v1 * v1;
                }
            }
        }
    }
    red[0][tid] = lsum; red[1][tid] = lsq;
    __syncthreads();
    for (int s2 = 128; s2 > 0; s2 >>= 1) {
        if (tid < s2) { red[0][tid] += red[0][tid + s2]; red[1][tid] += red[1][tid + s2]; }
        __syncthreads();
    }
    if (tid == 0) {
        atomicAdd(&stats1[2 * b], red[0][0]);
        atomicAdd(&stats1[2 * b + 1], red[1][0]);
    }
}

// ---------------------------------------------------------------------------
// conv_mfma v2: layers 2-4 (K=4,S=2). 128oc x 64t tile, same 2-phase dbuf
// structure as conv1_mfma. Input pair-interleaved f16.
// PAIRED: f16 pair-interleaved out; else fp32. LDS 43.5 KB -> 3 blocks/CU.
// ---------------------------------------------------------------------------
template <bool PAIRED>
__global__ __launch_bounds__(256, 3) void conv_mfma(
    const _Float16* __restrict__ x,
    const _Float16* __restrict__ w,
    _Float16* __restrict__ oh, float* __restrict__ oplain,
    float* __restrict__ stats, int Lin, int Lout, int nx)
{
    __shared__ _Float16 LW[2][2][4][128][8];   // 32 KB
    __shared__ _Float16 LX[2][8][272];         // 8.5 KB [buf][pl][t4]
    __shared__ float red[2][256];

    const int tid  = threadIdx.x;
    const int lane = tid & 63, wv = tid >> 6;
    const int m    = lane & 15, quad = lane >> 4;
    const int wv2  = wv >> 1, wvt = wv & 1;

    // chunked XCD swizzle (nwg = nx*64, always % 8 == 0), y fastest in chunk
    const int raw = blockIdx.x;
    const int chunk = (nx * 64) >> 3;
    const int cid = (raw & 7) * chunk + (raw >> 3);
    const int perb = nx * 4;
    const int b   = cid / perb;
    const int r2  = cid - b * perb;
    const int xt  = r2 >> 2, yt = r2 & 3;
    const int ocb = yt * 128;
    const int t0  = xt * 64;

    float4v acc[4][2];
#pragma unroll
    for (int i = 0; i < 4; ++i)
#pragma unroll
        for (int j = 0; j < 2; ++j) acc[i][j] = (float4v){0.f, 0.f, 0.f, 0.f};

    const int lim = (Lin - t0 * 2) * 2;        // valid f16s in padded row window
    const bool fullx = (272 <= lim);           // only last t-tile is partial
    const size_t rstride = (size_t)Lin * 2;

    // --- X stage state: 272 16B-units/iter; eA = tid, eB = tid+256 (tid<16)
    const int plA = tid / 34, uA = tid - plA * 34;
    const int uB  = tid + 18;                  // pl 7, valid only tid<16
    const _Float16* srcA = x + ((size_t)(b * 256) + plA) * rstride + t0 * 4 + uA * 8;
    const _Float16* srcB = x + ((size_t)(b * 256) + 7)   * rstride + t0 * 4 + uB * 8;
    half8v xr[2];

    // --- W stage state (w layout [oc][icp 256][8])
    const _Float16* wsrc[4];
#pragma unroll
    for (int r = 0; r < 4; ++r) {
        const int e = wv * 4 + r;
        const int oh2 = e & 1, q = (e >> 1) & 3, k32l = e >> 3;
        wsrc[r] = w + ((size_t)(ocb + oh2 * 64 + lane) * 256 + (k32l * 4 + q)) * 8;
    }

    auto stageW = [&](int buf) {
#pragma unroll
        for (int r = 0; r < 4; ++r) {
            const int e = wv * 4 + r;
            const int oh2 = e & 1, q = (e >> 1) & 3, k32l = e >> 3;
            GLOAD_LDS16(wsrc[r], &LW[buf][k32l][q][oh2 * 64][0]);
            wsrc[r] += 64;                     // 8 icp * 8
        }
    };
    auto loadX = [&]() {
        if (fullx) {
            xr[0] = *(const half8v*)srcA;
            if (tid < 16) xr[1] = *(const half8v*)srcB;
        } else {
#pragma unroll
            for (int k = 0; k < 8; ++k) xr[0][k] = (uA * 8 + k < lim) ? srcA[k] : (_Float16)0.f;
            if (tid < 16) {
#pragma unroll
                for (int k = 0; k < 8; ++k) xr[1][k] = (uB * 8 + k < lim) ? srcB[k] : (_Float16)0.f;
            }
        }
        srcA += 8 * rstride; srcB += 8 * rstride;
    };
    auto storeX = [&](int buf) {
        *(half8v*)&LX[buf][plA][uA * 8] = xr[0];
        if (tid < 16) *(half8v*)&LX[buf][7][uB * 8] = xr[1];
    };
    auto compute = [&](int buf) {
#pragma unroll
        for (int k32l = 0; k32l < 2; ++k32l) {
            half8v a4[4], bfv[2];
#pragma unroll
            for (int i = 0; i < 4; ++i)
                a4[i] = *(const half8v*)&LW[buf][k32l][quad][wv2 * 64 + i * 16 + m][0];
            const int pl = k32l * 4 + quad;
#pragma unroll
            for (int j = 0; j < 2; ++j) {
                const int tl = wvt * 32 + j * 16 + m;
                const half4v x0 = *(const half4v*)&LX[buf][pl][tl * 4];
                const half4v x1 = *(const half4v*)&LX[buf][pl][tl * 4 + 4];
                bfv[j] = __builtin_shufflevector(x0, x1, 0, 1, 2, 3, 4, 5, 6, 7);
            }
#pragma unroll
            for (int i = 0; i < 4; ++i)
#pragma unroll
                for (int j = 0; j < 2; ++j)
                    acc[i][j] = __builtin_amdgcn_mfma_f32_16x16x32_f16(a4[i], bfv[j], acc[i][j], 0, 0, 0);
        }
    };

    // prologue
    loadX(); stageW(0); storeX(0);
    __syncthreads();

    for (int it = 0; it < 32; it += 2) {
        loadX(); stageW(1);                    // it+1 < 32 always (it <= 30)
        compute(0);
        storeX(1);
        __syncthreads();
        const bool s2 = (it + 2 < 32);
        if (s2) { loadX(); stageW(0); }
        compute(1);
        if (s2) storeX(0);
        __syncthreads();
    }

    // --- epilogue
    float lsum = 0.f, lsq = 0.f;
    uint* ohU = (uint*)oh;
#pragma unroll
    for (int i = 0; i < 4; ++i) {
        const int ocb2 = ocb + wv2 * 64 + i * 16 + quad * 4;
#pragma unroll
        for (int j = 0; j < 2; ++j) {
            const int t = t0 + wvt * 32 + j * 16 + m;
            if (t < Lout) {
                if (PAIRED) {
#pragma unroll
                    for (int pr = 0; pr < 2; ++pr) {
                        const float v0 = acc[i][j][pr * 2], v1 = acc[i][j][pr * 2 + 1];
                        union { uint u; _Float16 h[2]; } pk;
                        pk.h[0] = (_Float16)v0; pk.h[1] = (_Float16)v1;
                        const uint p = (uint)((ocb2 >> 1) + pr);
                        ohU[((size_t)(b * 256 + p)) * Lout + t] = pk.u;
                        lsum += v0 + v1; lsq += v0 * v0 + v1 * v1;
                    }
                } else {
#pragma unroll
                    for (int r = 0; r < 4; ++r) {
                        const float v = acc[i][j][r];
                        oplain[((size_t)(b * 512 + ocb2 + r)) * Lout + t] = v;
                        lsum += v; lsq += v * v;
                    }
                }
            }
        }
    }
    red[0][tid] = lsum; red[1][tid] = lsq;
    __syncthreads();
    for (int s2 = 128; s2 > 0; s2 >>= 1) {
        if (tid < s2) { red[0][tid] += red[0][tid + s2]; red[1][tid] += red[1][tid + s2]; }
        __syncthreads();
    }
    if (tid == 0) {
        atomicAdd(&stats[2 * b], red[0][0]);
        atomicAdd(&stats[2 * b + 1], red[1][0]);
    }
}

// ---------------------------------------------------------------------------
// norm_pair: GN(1grp)+affine+ReLU in place on pair-interleaved f16.
// ---------------------------------------------------------------------------
__global__ __launch_bounds__(256) void norm_pair(
    uint* __restrict__ h, const float* __restrict__ stats,
    const float* __restrict__ gamma, const float* __restrict__ beta,
    int L, float invN)
{
    const int row = blockIdx.y;
    const int b = row >> 8, p = row & 255;
    const int t = blockIdx.x * 256 + threadIdx.x;
    if (t >= L) return;
    const int c0 = 2 * p, c1 = 2 * p + 1;
    const float mu = stats[2 * b] * invN;
    const float var = stats[2 * b + 1] * invN - mu * mu;
    const float rs = rsqrtf(var + 1e-5f);
    const float sc0 = rs * gamma[c0], sh0 = beta[c0] - mu * sc0;
    const float sc1 = rs * gamma[c1], sh1 = beta[c1] - mu * sc1;
    const size_t idx = (size_t)row * L + t;
    union { uint u; _Float16 h2[2]; } pk;
    pk.u = h[idx];
    const float n0 = fmaxf((float)pk.h2[0] * sc0 + sh0, 0.f);
    const float n1 = fmaxf((float)pk.h2[1] * sc1 + sh1, 0.f);
    pk.h2[0] = (_Float16)n0; pk.h2[1] = (_Float16)n1;
    h[idx] = pk.u;
}

// ---------------------------------------------------------------------------
// norm_feat: GN+affine+ReLU on plain fp32 features, in place.
// ---------------------------------------------------------------------------
__global__ __launch_bounds__(256) void norm_feat(
    float* __restrict__ h, const float* __restrict__ stats,
    const float* __restrict__ gamma, const float* __restrict__ beta,
    int L, float invN)
{
    const int row = blockIdx.y;
    const int b = row >> 9, oc = row & 511;
    const int t = blockIdx.x * 256 + threadIdx.x;
    if (t >= L) return;
    const float mu = stats[2 * b] * invN;
    const float var = stats[2 * b + 1] * invN - mu * mu;
    const float rs = rsqrtf(var + 1e-5f);
    const float sc = rs * gamma[oc];
    const float sh = beta[oc] - mu * sc;
    const size_t i = (size_t)row * L + t;
    const float v = h[i] * sc + sh;
    h[i] = v > 0.f ? v : 0.f;
}

// ---------------------------------------------------------------------------
// aa_kernel: row squared-norms of features.
// ---------------------------------------------------------------------------
__global__ __launch_bounds__(256) void aa_kernel(
    const float* __restrict__ fX, const float* __restrict__ fY,
    float* __restrict__ aaX, float* __restrict__ aaY)
{
    const int wave = threadIdx.x >> 6, lane = threadIdx.x & 63;
    const int R = blockIdx.x * 4 + wave;
    const float* f = (R < 8192) ? fX : fY;
    const int r = R & 8191;
    const float* row = f + (size_t)r * 198;
    float s = 0.f;
#pragma unroll
    for (int k = 0; k < 4; ++k) {
        const int j = lane + 64 * k;
        if (j < 198) { const float v = row[j]; s += v * v; }
    }
#pragma unroll
    for (int off = 32; off > 0; off >>= 1) s += __shfl_xor(s, off);
    if (lane == 0) ((R < 8192) ? aaX : aaY)[r] = s;
}

// ---------------------------------------------------------------------------
// cost_kernel: M = f16( min(50 * max(aa[n]+bb[m]-2<p,q>, 0), 65000) ) == 100*C
// ---------------------------------------------------------------------------
__global__ __launch_bounds__(256) void cost_kernel(
    const float* __restrict__ fX, const float* __restrict__ fY,
    const float* __restrict__ aaX, const float* __restrict__ aaY,
    _Float16* __restrict__ Cxy, _Float16* __restrict__ Cxx,
    _Float16* __restrict__ Cyy, _Float16* __restrict__ CTxy)
{
    const int z = blockIdx.z;
    const int mat = z >> 4, b = z & 15;
    const float *P, *Q, *aP, *aQ;
    _Float16 *Cm, *CT = nullptr;
    if (mat == 0) { P = fX; Q = fY; aP = aaX; aQ = aaY; Cm = Cxy; CT = CTxy; }
    else if (mat == 1) { P = fX; Q = fX; aP = aaX; aQ = aaX; Cm = Cxx; }
    else { P = fY; Q = fY; aP = aaY; aQ = aaY; Cm = Cyy; }

    const int n0 = blockIdx.x * 32, m0 = blockIdx.y * 32;
    __shared__ float LP[32][201], LQ[32][201];
    const int tid = threadIdx.x;
    for (int e = tid; e < 32 * 198; e += 256) {
        const int r = e / 198, d = e % 198;
        LP[r][d] = P[((size_t)b * 512 + n0 + r) * 198 + d];
        LQ[r][d] = Q[((size_t)b * 512 + m0 + r) * 198 + d];
    }
    __syncthreads();

    const int tx = tid & 31, ty = tid >> 5;
    float dot[4] = {0.f, 0.f, 0.f, 0.f};
    for (int d = 0; d < 198; ++d) {
        const float qv = LQ[tx][d];
#pragma unroll
        for (int q = 0; q < 4; ++q) dot[q] += LP[ty + 8 * q][d] * qv;
    }
    const int mm = m0 + tx;
    const float bbm = aQ[b * 512 + mm];
#pragma unroll
    for (int q = 0; q < 4; ++q) {
        const int n = n0 + ty + 8 * q;
        float c = 50.f * fmaxf(aP[b * 512 + n] + bbm - 2.f * dot[q], 0.f);  // == 100*C
        c = fminf(c, 65000.f);
        const _Float16 ch = (_Float16)c;
        Cm[((size_t)b * 512 + n) * 512 + mm] = ch;
        if (CT) CT[((size_t)b * 512 + mm) * 512 + n] = ch;
    }
}

// ---------------------------------------------------------------------------
// Per-row half-update (two-pass max-then-sum; same math as proven version).
// dst[p*512+i] = eps*log512 - eps*LSE_j( 400*src[j] - 4*M100[i,j] )
// ---------------------------------------------------------------------------
static __device__ __forceinline__ void sink_rows(
    float* __restrict__ dst, const float* __restrict__ src,
    const _Float16* __restrict__ Mb, int p, int i0, int lane)
{
    const float* sp = src + (size_t)p * 512;
    float s8[8];
    {
        const float4 sa = *(const float4*)&sp[lane * 8];
        const float4 sb = *(const float4*)&sp[lane * 8 + 4];
        s8[0]=sa.x*400.f; s8[1]=sa.y*400.f; s8[2]=sa.z*400.f; s8[3]=sa.w*400.f;
        s8[4]=sb.x*400.f; s8[5]=sb.y*400.f; s8[6]=sb.z*400.f; s8[7]=sb.w*400.f;
    }
#pragma unroll
    for (int rr = 0; rr < 4; ++rr) {
        const int i = i0 + rr;
        const half8v rv = *(const half8v*)(Mb + (size_t)i * 512 + lane * 8);
        float a8[8];
#pragma unroll
        for (int k = 0; k < 8; ++k) a8[k] = fmaf(-4.f, (float)rv[k], s8[k]);
        float mx = a8[0];
#pragma unroll
        for (int k = 1; k < 8; ++k) mx = fmaxf(mx, a8[k]);
        // wave-global max (fmax butterfly, no exps)
#pragma unroll
        for (int off = 32; off > 0; off >>= 1) mx = fmaxf(mx, __shfl_xor(mx, off));
        // sum of exp(a - global max)
        float ss = 0.f;
#pragma unroll
        for (int k = 0; k < 8; ++k) ss += __expf(a8[k] - mx);
#pragma unroll
        for (int off = 32; off > 0; off >>= 1) ss += __shfl_xor(ss, off);
        if (lane == 0)
            dst[(size_t)p * 512 + i] = EPS_LOG512 - EPS_SINK * (mx + logf(ss));
    }
}

// ---------------------------------------------------------------------------
// sink_update: one half-update per launch; grid (32,48), 256 thr.
// ---------------------------------------------------------------------------
__global__ __launch_bounds__(256) void sink_update(
    float* __restrict__ dst, const float* __restrict__ src,
    const _Float16* __restrict__ M0, const _Float16* __restrict__ M1,
    const _Float16* __restrict__ M2)
{
    const int p = blockIdx.y;
    const int mat = p >> 4, b = p & 15;
    const _Float16* M = ((mat == 0) ? M0 : ((mat == 1) ? M1 : M2)) + (size_t)b * 512 * 512;
    const int wave = threadIdx.x >> 6, lane = threadIdx.x & 63;
    const int i0 = blockIdx.x * 16 + wave * 4;
    sink_rows(dst, src, M, p, i0, lane);
}

// ---------------------------------------------------------------------------
__global__ __launch_bounds__(256) void final_kernel(
    const float* __restrict__ f, const float* __restrict__ g,
    float* __restrict__ out)
{
    const int b = blockIdx.x, tid = threadIdx.x;
    __shared__ float red[256];
    float a = 0.f;
    for (int n = tid; n < 512; n += 256) {
        const float xy = f[(0 * 16 + b) * 512 + n] + g[(0 * 16 + b) * 512 + n];
        const float xx = f[(1 * 16 + b) * 512 + n] + g[(1 * 16 + b) * 512 + n];
        const float yy = f[(2 * 16 + b) * 512 + n] + g[(2 * 16 + b) * 512 + n];
        a += xy - 0.5f * (xx + yy);
    }
    red[tid] = a;
    __syncthreads();
    for (int s2 = 128; s2 > 0; s2 >>= 1) {
        if (tid < s2) red[tid] += red[tid + s2];
        __syncthreads();
    }
    if (tid == 0) out[b] = red[0] * (1.0f / 512.0f);
}

// ---------------------------------------------------------------------------
extern "C" void kernel_launch(void* const* d_in, const int* in_sizes, int n_in,
                              void* d_out, int out_size, void* d_ws, size_t ws_size,
                              hipStream_t stream)
{
    (void)in_sizes; (void)n_in; (void)out_size; (void)ws_size;
    char* ws = (char*)d_ws;
    const float* yhat = (const float*)d_in[0];
    const float* ysig = (const float*)d_in[1];
    const float* Wl[5]; const float* gl[5]; const float* bl[5];
    for (int i = 0; i < 5; ++i) {
        Wl[i] = (const float*)d_in[2 + 3 * i];
        gl[i] = (const float*)d_in[3 + 3 * i];
        bl[i] = (const float*)d_in[4 + 3 * i];
    }
    float* out = (float*)d_out;
    float* statsA = (float*)(ws + O_STATS);

    _Float16* w1 = (_Float16*)(ws + O_W1);
    _Float16* w2 = (_Float16*)(ws + O_W2);
    _Float16* w3 = (_Float16*)(ws + O_W3);
    _Float16* w4 = (_Float16*)(ws + O_W4);
    _Float16* h0 = (_Float16*)(ws + O_H0);
    _Float16* h1 = (_Float16*)(ws + O_H1);
    _Float16* h2 = (_Float16*)(ws + O_H2);
    _Float16* h3 = (_Float16*)(ws + O_H3);

    hipMemsetAsync(statsA, 0, 512 * sizeof(float), stream);
    prep_w<<<dim3(1024, 4), 256, 0, stream>>>(Wl[1], Wl[2], Wl[3], Wl[4],
        w1, w2, w3, w4);

    for (int s = 0; s < 2; ++s) {
        const float* wav = (s == 0) ? yhat : ysig;
        float* st = statsA + (size_t)s * 160;
        float* ft = (float*)(ws + ((s == 0) ? O_FEATX : O_FEATY));

        conv0_store<<<dim3(25, 16), 256, 0, stream>>>(wav, Wl[0], h0, st);
        norm_h0<<<dim3(4, 8192), 256, 0, stream>>>(h0, st, gl[0], bl[0]);

        conv1_mfma<<<dim3(832), 256, 0, stream>>>(h0, w1, h1, st + 32);
        norm_pair<<<dim3(7, 4096), 256, 0, stream>>>(
            (uint*)h1, st + 32, gl[1], bl[1], 1598, 1.f / (512.f * 1598.f));

        conv_mfma<true><<<dim3(832), 256, 0, stream>>>(
            h1, w2, h2, nullptr, st + 64, 1598, 798, 13);
        norm_pair<<<dim3(4, 4096), 256, 0, stream>>>(
            (uint*)h2, st + 64, gl[2], bl[2], 798, 1.f / (512.f * 798.f));

        conv_mfma<true><<<dim3(448), 256, 0, stream>>>(
            h2, w3, h3, nullptr, st + 96, 798, 398, 7);
        norm_pair<<<dim3(2, 4096), 256, 0, stream>>>(
            (uint*)h3, st + 96, gl[3], bl[3], 398, 1.f / (512.f * 398.f));

        conv_mfma<false><<<dim3(256), 256, 0, stream>>>(
            h3, w4, nullptr, ft, st + 128, 398, 198, 4);
        norm_feat<<<dim3(1, 8192), 256, 0, stream>>>(
            ft, st + 128, gl[4], bl[4], 198, 1.f / (512.f * 198.f));
    }

    float* featX = (float*)(ws + O_FEATX);
    float* featY = (float*)(ws + O_FEATY);
    aa_kernel<<<4096, 256, 0, stream>>>(featX, featY, (float*)(ws + O_AAX), (float*)(ws + O_AAY));
    cost_kernel<<<dim3(16, 16, 48), 256, 0, stream>>>(
        featX, featY, (float*)(ws + O_AAX), (float*)(ws + O_AAY),
        (_Float16*)(ws + O_CXY), (_Float16*)(ws + O_CXX), (_Float16*)(ws + O_CYY),
        (_Float16*)(ws + O_CTXY));

    hipMemsetAsync(ws + O_F, 0, 2 * 24576 * sizeof(float), stream);

    float* fptr = (float*)(ws + O_F);
    float* gptr = (float*)(ws + O_G);
    _Float16* cxy  = (_Float16*)(ws + O_CXY);
    _Float16* ctxy = (_Float16*)(ws + O_CTXY);
    _Float16* cxx  = (_Float16*)(ws + O_CXX);
    _Float16* cyy  = (_Float16*)(ws + O_CYY);

    for (int it = 0; it < 50; ++it) {
        sink_update<<<dim3(32, 48), 256, 0, stream>>>(gptr, fptr, ctxy, cxx, cyy);
        sink_update<<<dim3(32, 48), 256, 0, stream>>>(fptr, gptr, cxy, cxx, cyy);
    }

    final_kernel<<<16, 256, 0, stream>>>(fptr, gptr, out);
}